// Round 15
// baseline (139.748 us; speedup 1.0000x reference)
//
#include <hip/hip_runtime.h>
#include <hip/hip_bf16.h>

// LeNet-5 forward, fully fused. ROUND 28: CONV1 SINGLE-PASS (kc-major, 12 nt).
//
// Post-mortems driving this round:
//  r27 (58.8us fused, 127.5 total, BEST): native bf16 cvt isolated at ~2.4us.
//  Walls (all measured): registers cap 4 waves/SIMD -- ANY in-flight-depth
//    increase in conv1/conv2 spills (r15/r16/r17/r26); LDS shrink useless
//    (VGPR caps 16 waves/CU); pipes <45%; HBM 1%.
//  Remaining modeled slack: conv1 loads each A-frag pair TWICE (9 kc x 2
//    g-passes = 18 serial global-load waits; A depends only on kc).
//
// Round-28: swap conv1's loops -- ONE kc-loop over all 12 nt tiles.
//  * Serial A-wait count 18 -> 9 (halves conv1's load-latency exposure).
//  * acc1[12][2] = 96 AGPR live; conv1 live ~120 < 128. This is STATIC
//    accumulator growth (conv2's clean 110-reg shape proves the pattern),
//    not load-in-flight depth (the four spill incidents' mechanism).
//  * Tripwire: WRITE_SIZE >= 1MB => spilled; revert to r27, declare plateau.
//  * everything else = r27 verbatim.
//
// Layouts: conv1 as GEMM (row-only im2col), banded weights K=288, N=192.
//   xbf16 global [B][800] (tail zeroed by prep_k);
//   h1 bf16 19x248 ([x*12+c], c-pads+row-pads zeroed) per wave;
//   h2 bf16 10x248 ([x*20+c]) overlays own h1; h3 bf16 736 overlays own h1.
//   All K-padding baked into pre-packed weights (zeros).

typedef short s16x4 __attribute__((ext_vector_type(4)));
typedef short s16x8 __attribute__((ext_vector_type(8)));
typedef float f32x4 __attribute__((ext_vector_type(4)));

#define ROW1 248
#define ROW2 248
#define H1SZ 4712           // 19*248
#define SM_ELEMS 9424       // 2*H1SZ -> 18848 B
#define XBSZ 800            // padded bf16 image stride
#define WPREP_BLOCKS 502    // 502*256 = 128512 weight elems (incl. wf frags)

static __device__ __forceinline__ unsigned short f2bf(float f) {
    __hip_bfloat16 h = __float2bfloat16(f);    // RNE, native cvt instruction
    union { __hip_bfloat16 h; unsigned short u; } v; v.h = h;
    return v.u;
}

static __device__ __forceinline__ s16x8 cat8(s16x4 lo, s16x4 hi) {
    return __builtin_shufflevector(lo, hi, 0, 1, 2, 3, 4, 5, 6, 7);
}

// ---- merged prep: weights (blocks [0,502)) + image cvt (rest) -------------
// wbuf ushort: [0,40960) conv2 B-frags, [40960,61440) conv3 B-frags,
//              [61440,116736) conv1 banded B-frags (wband),
//              [116736,128512) fc wf B-frags (23 kc x 512, K=736 padded).
// 16x16x32 B-frag convention: n = nt*16 + (lane&15), k = kc*32 + quad*8 + t.
__global__ __launch_bounds__(256) void prep_k(const float* __restrict__ w1,
                                              const float* __restrict__ w2,
                                              const float* __restrict__ w3,
                                              const float* __restrict__ wf,
                                              const float* __restrict__ x,
                                              unsigned short* __restrict__ wbuf,
                                              unsigned short* __restrict__ xb,
                                              int total4) {
    if (blockIdx.x < WPREP_BLOCKS) {
        int e = blockIdx.x * 256 + threadIdx.x;
        if (e < 40960) {                       // conv2: j=k/12, c=k%12
            int t = e & 7, lane = (e >> 3) & 63, nt = (e >> 9) & 1;
            int ck = (e >> 10) & 3, i = e >> 12;
            int k = ck * 32 + ((lane >> 4) & 3) * 8 + t;
            int o = nt * 16 + (lane & 15);
            int j = k / 12, c = k % 12;
            float val = (j < 10 && c < 10 && o < 20) ? w2[o * 1000 + c * 100 + i * 10 + j] : 0.f;
            wbuf[e] = f2bf(val);
        } else if (e < 61440) {                // conv3: j=k/20, c=k%20
            int e2 = e - 40960;
            int t = e2 & 7, lane = (e2 >> 3) & 63, nt = (e2 >> 9) & 1;
            int ck = (e2 >> 10) & 3, i = e2 >> 12;
            int k = ck * 32 + ((lane >> 4) & 3) * 8 + t;
            int o = nt * 16 + (lane & 15);
            int j = k / 20, c = k % 20;
            float val = (j < 5 && o < 20) ? w3[o * 500 + c * 25 + i * 5 + j] : 0.f;
            wbuf[e] = f2bf(val);
        } else if (e < 116736) {               // conv1 band: [nt(12)][kc(9)][lane][t]
            int e2 = e - 61440;                // < 55296
            int t = e2 & 7, lane = (e2 >> 3) & 63;
            int kc = (e2 >> 9) % 9, nt = (e2 >> 9) / 9;
            int n = nt * 16 + (lane & 15);
            int k = kc * 32 + ((lane >> 4) & 3) * 8 + t;
            float val = 0.f;
            if (n < 190 && k < 280) {
                int ox = n / 10, o = n - ox * 10;
                int i = k / 28, xc = k - i * 28;
                int j = xc - ox;
                if (j >= 0 && j < 10) val = w1[o * 100 + i * 10 + j];
            }
            wbuf[61440 + e2] = f2bf(val);
        } else {                               // fc wf frags: [kc(23)][lane][t]
            int e2 = e - 116736;               // < 11776
            int t = e2 & 7, lane = (e2 >> 3) & 63;
            int kc = e2 >> 9;                  // [0,23)
            int o = lane & 15;
            int k = kc * 32 + ((lane >> 4) & 3) * 8 + t;
            float val = (o < 10 && k < 720) ? wf[o * 720 + k] : 0.f;
            wbuf[116736 + e2] = f2bf(val);
        }
    } else {                                   // image cvt: one s16x4 / thread
        int e4 = (blockIdx.x - WPREP_BLOCKS) * 256 + threadIdx.x;
        if (e4 >= total4) return;
        int img = e4 / 200, i4 = e4 - img * 200;
        s16x4 p = {0, 0, 0, 0};
        if (i4 < 196) {
            float4 v = *(const float4*)(x + (size_t)img * 784 + i4 * 4);
            p[0] = (short)f2bf(v.x); p[1] = (short)f2bf(v.y);
            p[2] = (short)f2bf(v.z); p[3] = (short)f2bf(v.w);
        }
        *(s16x4*)(xb + (size_t)img * XBSZ + i4 * 4) = p;
    }
}

// --------------------------- the fused kernel ------------------------------
__global__ __launch_bounds__(128, 4) void fused_k(const unsigned short* __restrict__ xbf,
                                                  const float* __restrict__ b1,
                                                  const unsigned short* __restrict__ wbuf2,
                                                  const unsigned short* __restrict__ wbuf3,
                                                  const unsigned short* __restrict__ wband,
                                                  const unsigned short* __restrict__ wfb,
                                                  const float* __restrict__ b2,
                                                  const float* __restrict__ b3,
                                                  const float* __restrict__ bf,
                                                  float* __restrict__ out) {
    __shared__ __align__(16) unsigned short sm16[SM_ELEMS];

    const int tid = threadIdx.x;
    const int wave = tid >> 6, lane = tid & 63;
    const int quad = lane >> 4, lm = lane & 15;
    const int img = blockIdx.x * 2 + wave;             // this wave's image

    unsigned short* h1w = sm16 + wave * H1SZ;          // own 4712-elem region

    // ---- zero h1 row pads + c-pads (before conv1 epilogue writes) ---------
    for (int e = lane; e < 95; e += 64) {              // row pads [228,248) x 19
        int row = e / 5, seg = e - row * 5;
        *(s16x4*)(h1w + row * ROW1 + 228 + seg * 4) = (s16x4){0, 0, 0, 0};
    }
    for (int e = lane; e < 361; e += 64) {             // c-pads (oy,ox,[10,12))
        int oy = e / 19, ox = e - oy * 19;
        *(unsigned int*)(h1w + oy * ROW1 + ox * 12 + 10) = 0u;
    }

    // ---- conv1 MFMA  M=32(19), N=192(190), K=288(280) ---------------------
    // SINGLE kc-major pass: A-frag pair loaded ONCE per kc (9 serial waits,
    // was 18), feeding all 12 nt tiles. acc1[12][2] = 96 AGPR (static).
    {
        const unsigned short* xg = xbf + (size_t)img * XBSZ;
        const int ab0 = lm * 28 + quad * 8;            // <= 444
        int r1 = lm + 16; if (r1 > 18) r1 = 18;        // clamp pad rows
        const int ab1 = r1 * 28 + quad * 8;            // <= 528; +256+7 <= 791 < 800
        const unsigned short* wb = wband + lane * 8;
        f32x4 acc1[12][2] = {};
#pragma unroll 1
        for (int kc = 0; kc < 9; ++kc) {
            s16x8 a0 = cat8(*(const s16x4*)(xg + ab0 + kc * 32),
                            *(const s16x4*)(xg + ab0 + kc * 32 + 4));
            s16x8 a1 = cat8(*(const s16x4*)(xg + ab1 + kc * 32),
                            *(const s16x4*)(xg + ab1 + kc * 32 + 4));
#pragma unroll
            for (int q = 0; q < 12; ++q) {
                s16x8 bw = *(const s16x8*)(wb + (q * 9 + kc) * 512);
                acc1[q][0] = __builtin_amdgcn_mfma_f32_16x16x32_bf16(a0, bw, acc1[q][0], 0, 0, 0);
                acc1[q][1] = __builtin_amdgcn_mfma_f32_16x16x32_bf16(a1, bw, acc1[q][1], 0, 0, 0);
            }
        }
#pragma unroll
        for (int q = 0; q < 12; ++q) {
            int n = q * 16 + lm;
            if (n < 190) {
                int ox = n / 10, o = n - ox * 10;
                float bias = b1[o];
#pragma unroll
                for (int mt = 0; mt < 2; ++mt) {
#pragma unroll
                    for (int r = 0; r < 4; ++r) {
                        int oy = mt * 16 + quad * 4 + r;
                        if (oy < 19)
                            h1w[oy * ROW1 + ox * 12 + o] =
                                f2bf(fmaxf(acc1[q][mt][r] + bias, 0.f));
                    }
                }
            }
        }
    }
    // no runtime barrier: own region, per-wave in-order LDS.

    // ---- conv2 MFMA  M=112(100), N=32(20), K=1280(1000) -------------------
    // 7 m-tiles, single-buffered af[7] (clean shape), dist-1 weights.
    int abase[7];
#pragma unroll
    for (int mt = 0; mt < 7; ++mt) {
        int m = mt * 16 + lm; if (m > 99) m = 99;
        int y = m / 10, xx = m - 10 * y;
        abase[mt] = y * ROW1 + xx * 12 + quad * 8;
    }
    f32x4 acc[7][2] = {};
    {
        const unsigned short* wptr = wbuf2 + lane * 8;
        s16x8 wc0 = *(const s16x8*)(wptr);
        s16x8 wc1 = *(const s16x8*)(wptr + 512);
#pragma unroll
        for (int it = 0; it < 40; ++it) {
            s16x8 wn0 = *(const s16x8*)(wptr + (it + 1) * 1024);   // tail->conv3 region
            s16x8 wn1 = *(const s16x8*)(wptr + (it + 1) * 1024 + 512);
            const unsigned short* sb = h1w + (it >> 2) * ROW1 + (it & 3) * 32;
            s16x8 af[7];
#pragma unroll
            for (int mt = 0; mt < 7; ++mt)
                af[mt] = cat8(*(const s16x4*)(sb + abase[mt]),
                              *(const s16x4*)(sb + abase[mt] + 4));
            __builtin_amdgcn_s_setprio(1);
#pragma unroll
            for (int mt = 0; mt < 7; ++mt) {
                acc[mt][0] = __builtin_amdgcn_mfma_f32_16x16x32_bf16(af[mt], wc0, acc[mt][0], 0, 0, 0);
                acc[mt][1] = __builtin_amdgcn_mfma_f32_16x16x32_bf16(af[mt], wc1, acc[mt][1], 0, 0, 0);
            }
            __builtin_amdgcn_s_setprio(0);
            wc0 = wn0; wc1 = wn1;
        }
    }

    // ---- scatter conv2 -> h2 ([x*20+c], overlays own h1) ------------------
    // h2 cols [200,248) keep stale finite h1 data; weights there are zero.
    unsigned short* h2w = h1w;
#pragma unroll
    for (int mt = 0; mt < 7; ++mt) {
#pragma unroll
        for (int nt = 0; nt < 2; ++nt) {
            int o = nt * 16 + lm;
            if (o < 20) {
                float bias = b2[o];
#pragma unroll
                for (int r = 0; r < 4; ++r) {
                    int pos = mt * 16 + quad * 4 + r;
                    if (pos < 100) {
                        int y2 = pos / 10, x2 = pos - 10 * y2;
                        h2w[y2 * ROW2 + x2 * 20 + o] =
                            f2bf(fmaxf(acc[mt][nt][r] + bias, 0.f));
                    }
                }
            }
        }
    }

    // ---- conv3 MFMA  M=48(36), N=32(20), K=640(500) -----------------------
    // dist-2 weight ring (3 pairs live): ~300cy cover >= L2 latency.
    int abase3[3];
#pragma unroll
    for (int mt = 0; mt < 3; ++mt) {
        int m = mt * 16 + lm; if (m > 35) m = 35;
        int oy = m / 6, ox = m - 6 * oy;
        abase3[mt] = oy * ROW2 + ox * 20 + quad * 8;
    }
    f32x4 acc3[3][2] = {};
    {
        const unsigned short* wptr = wbuf3 + lane * 8;
        s16x8 wA0 = *(const s16x8*)(wptr);
        s16x8 wA1 = *(const s16x8*)(wptr + 512);
        s16x8 wB0 = *(const s16x8*)(wptr + 1024);
        s16x8 wB1 = *(const s16x8*)(wptr + 1024 + 512);
#pragma unroll
        for (int it = 0; it < 20; ++it) {
            // prefetch it+2 (tail reads land in wband region: valid memory)
            s16x8 wC0 = *(const s16x8*)(wptr + (it + 2) * 1024);
            s16x8 wC1 = *(const s16x8*)(wptr + (it + 2) * 1024 + 512);
            const unsigned short* sb = h2w + (it >> 2) * ROW2 + (it & 3) * 32;
            s16x8 af[3];
#pragma unroll
            for (int mt = 0; mt < 3; ++mt)
                af[mt] = cat8(*(const s16x4*)(sb + abase3[mt]),
                              *(const s16x4*)(sb + abase3[mt] + 4));
            __builtin_amdgcn_s_setprio(1);
#pragma unroll
            for (int mt = 0; mt < 3; ++mt) {
                acc3[mt][0] = __builtin_amdgcn_mfma_f32_16x16x32_bf16(af[mt], wA0, acc3[mt][0], 0, 0, 0);
                acc3[mt][1] = __builtin_amdgcn_mfma_f32_16x16x32_bf16(af[mt], wA1, acc3[mt][1], 0, 0, 0);
            }
            __builtin_amdgcn_s_setprio(0);
            wA0 = wB0; wA1 = wB1;                      // rotate ring
            wB0 = wC0; wB1 = wC1;
        }
    }

    // ---- conv3 epilogue -> h3b[o*36+pos] (BF16, relu, overlays own h1) ----
    unsigned short* h3b = h1w;                         // bf16, k-ordered
#pragma unroll
    for (int mt = 0; mt < 3; ++mt) {
#pragma unroll
        for (int nt = 0; nt < 2; ++nt) {
            int o = nt * 16 + lm;
            if (o < 20) {
                float b3v = b3[o];
#pragma unroll
                for (int r = 0; r < 4; ++r) {
                    int pos = mt * 16 + quad * 4 + r;
                    if (pos < 36)
                        h3b[o * 36 + pos] = f2bf(fmaxf(acc3[mt][nt][r] + b3v, 0.f));
                }
            }
        }
    }
    if (lane < 16) h3b[720 + lane] = 0;                // K pad [720,736)

    // ---- fc as MFMA GEMV: broadcast-A (all 16 m-rows = h3) x wf B-frags ---
    // C[row][col] identical across rows; lane holds col = lane&15 in acc[0]
    // (row = quad*4). Lanes 0-9 store out directly. K = 736 = 23 kc.
    {
        const unsigned short* wfp = wfb + lane * 8;
        f32x4 accf = {};
        s16x8 wc = *(const s16x8*)(wfp);
#pragma unroll
        for (int kc = 0; kc < 23; ++kc) {
            s16x8 wn;
            if (kc < 22) wn = *(const s16x8*)(wfp + (kc + 1) * 512);
            s16x8 ah = cat8(*(const s16x4*)(h3b + kc * 32 + quad * 8),
                            *(const s16x4*)(h3b + kc * 32 + quad * 8 + 4));
            accf = __builtin_amdgcn_mfma_f32_16x16x32_bf16(ah, wc, accf, 0, 0, 0);
            if (kc < 22) wc = wn;
        }
        if (lane < 10)
            out[(size_t)img * 10 + lane] = accf[0] + bf[lane];
    }
}

extern "C" void kernel_launch(void* const* d_in, const int* in_sizes, int n_in,
                              void* d_out, int out_size, void* d_ws, size_t ws_size,
                              hipStream_t stream) {
    (void)n_in; (void)out_size; (void)ws_size;
    const float* x  = (const float*)d_in[0];
    const float* w1 = (const float*)d_in[1];
    const float* b1 = (const float*)d_in[2];
    const float* w2 = (const float*)d_in[3];
    const float* b2 = (const float*)d_in[4];
    const float* w3 = (const float*)d_in[5];
    const float* b3 = (const float*)d_in[6];
    const float* wf = (const float*)d_in[7];
    const float* bf = (const float*)d_in[8];
    float* out = (float*)d_out;

    const int B = in_sizes[0] / 784;                   // 4096

    unsigned short* wbuf  = (unsigned short*)d_ws;     // 128512 ushorts = 257 KB
    unsigned short* xbf16 = wbuf + 128512;             // B*800 ushorts = 6.4 MB

    const int total4 = B * 200;                        // s16x4 units
    const int xblocks = (total4 + 255) / 256;
    prep_k<<<WPREP_BLOCKS + xblocks, 256, 0, stream>>>(w1, w2, w3, wf, x,
                                                       wbuf, xbf16, total4);
    fused_k<<<B / 2, 128, 0, stream>>>(xbf16, b1, wbuf, wbuf + 40960,
                                       wbuf + 61440, wbuf + 116736,
                                       b2, b3, bf, out);
}

// Round 16
// 126.813 us; speedup vs baseline: 1.1020x; 1.1020x over previous
//
#include <hip/hip_runtime.h>
#include <hip/hip_bf16.h>

// LeNet-5 forward, fully fused. ROUND 29 = r27 RESTORED (session best).
//
// r28 post-mortem: conv1 kc-major acc1[12][2] (96 AGPR) SPILLED (WRITE
// 192->2240 KB, fused 58.8->68.2us) -- tripwire fired; reverted per the
// pre-committed rule. Fifth independent confirmation that the 128-unified-
// register budget at 4 waves/SIMD is the binding wall in EVERY direction:
// r15 (acc growth), r16 (deep rings), r17 (f32 temps), r26 (A-prefetch),
// r28 (kc-major acc). Register ledger fully mapped.
//
// r27 state (proven): 58.8us fused / 127.5us total; WRITE 192KB (no spill),
// MfmaUtil 42.9%, VALUBusy 29%, occ 36%, HBM 1%, conflicts trivial.
// All captured levers: zero-barrier wave-owns-image dataflow, exact
// 8-block/CU residency, ROW1=248 conflict-free, conv2 af[7]+dist-1,
// conv3 dist-2 ring, setprio MFMA bursts, fc-on-MFMA (broadcast-A GEMV),
// native bf16 cvt, merged prep kernel (2 dispatches total).
//
// Layouts: conv1 as GEMM (row-only im2col), banded weights K=288, N=192.
//   xbf16 global [B][800] (tail zeroed by prep_k);
//   h1 bf16 19x248 ([x*12+c], c-pads+row-pads zeroed) per wave;
//   h2 bf16 10x248 ([x*20+c]) overlays own h1; h3 bf16 736 overlays own h1.
//   All K-padding baked into pre-packed weights (zeros).

typedef short s16x4 __attribute__((ext_vector_type(4)));
typedef short s16x8 __attribute__((ext_vector_type(8)));
typedef float f32x4 __attribute__((ext_vector_type(4)));

#define ROW1 248
#define ROW2 248
#define H1SZ 4712           // 19*248
#define SM_ELEMS 9424       // 2*H1SZ -> 18848 B
#define XBSZ 800            // padded bf16 image stride
#define WPREP_BLOCKS 502    // 502*256 = 128512 weight elems (incl. wf frags)

static __device__ __forceinline__ unsigned short f2bf(float f) {
    __hip_bfloat16 h = __float2bfloat16(f);    // RNE, native cvt instruction
    union { __hip_bfloat16 h; unsigned short u; } v; v.h = h;
    return v.u;
}

static __device__ __forceinline__ s16x8 cat8(s16x4 lo, s16x4 hi) {
    return __builtin_shufflevector(lo, hi, 0, 1, 2, 3, 4, 5, 6, 7);
}

// ---- merged prep: weights (blocks [0,502)) + image cvt (rest) -------------
// wbuf ushort: [0,40960) conv2 B-frags, [40960,61440) conv3 B-frags,
//              [61440,116736) conv1 banded B-frags (wband),
//              [116736,128512) fc wf B-frags (23 kc x 512, K=736 padded).
// 16x16x32 B-frag convention: n = nt*16 + (lane&15), k = kc*32 + quad*8 + t.
__global__ __launch_bounds__(256) void prep_k(const float* __restrict__ w1,
                                              const float* __restrict__ w2,
                                              const float* __restrict__ w3,
                                              const float* __restrict__ wf,
                                              const float* __restrict__ x,
                                              unsigned short* __restrict__ wbuf,
                                              unsigned short* __restrict__ xb,
                                              int total4) {
    if (blockIdx.x < WPREP_BLOCKS) {
        int e = blockIdx.x * 256 + threadIdx.x;
        if (e < 40960) {                       // conv2: j=k/12, c=k%12
            int t = e & 7, lane = (e >> 3) & 63, nt = (e >> 9) & 1;
            int ck = (e >> 10) & 3, i = e >> 12;
            int k = ck * 32 + ((lane >> 4) & 3) * 8 + t;
            int o = nt * 16 + (lane & 15);
            int j = k / 12, c = k % 12;
            float val = (j < 10 && c < 10 && o < 20) ? w2[o * 1000 + c * 100 + i * 10 + j] : 0.f;
            wbuf[e] = f2bf(val);
        } else if (e < 61440) {                // conv3: j=k/20, c=k%20
            int e2 = e - 40960;
            int t = e2 & 7, lane = (e2 >> 3) & 63, nt = (e2 >> 9) & 1;
            int ck = (e2 >> 10) & 3, i = e2 >> 12;
            int k = ck * 32 + ((lane >> 4) & 3) * 8 + t;
            int o = nt * 16 + (lane & 15);
            int j = k / 20, c = k % 20;
            float val = (j < 5 && o < 20) ? w3[o * 500 + c * 25 + i * 5 + j] : 0.f;
            wbuf[e] = f2bf(val);
        } else if (e < 116736) {               // conv1 band: [nt(12)][kc(9)][lane][t]
            int e2 = e - 61440;                // < 55296
            int t = e2 & 7, lane = (e2 >> 3) & 63;
            int kc = (e2 >> 9) % 9, nt = (e2 >> 9) / 9;
            int n = nt * 16 + (lane & 15);
            int k = kc * 32 + ((lane >> 4) & 3) * 8 + t;
            float val = 0.f;
            if (n < 190 && k < 280) {
                int ox = n / 10, o = n - ox * 10;
                int i = k / 28, xc = k - i * 28;
                int j = xc - ox;
                if (j >= 0 && j < 10) val = w1[o * 100 + i * 10 + j];
            }
            wbuf[61440 + e2] = f2bf(val);
        } else {                               // fc wf frags: [kc(23)][lane][t]
            int e2 = e - 116736;               // < 11776
            int t = e2 & 7, lane = (e2 >> 3) & 63;
            int kc = e2 >> 9;                  // [0,23)
            int o = lane & 15;
            int k = kc * 32 + ((lane >> 4) & 3) * 8 + t;
            float val = (o < 10 && k < 720) ? wf[o * 720 + k] : 0.f;
            wbuf[116736 + e2] = f2bf(val);
        }
    } else {                                   // image cvt: one s16x4 / thread
        int e4 = (blockIdx.x - WPREP_BLOCKS) * 256 + threadIdx.x;
        if (e4 >= total4) return;
        int img = e4 / 200, i4 = e4 - img * 200;
        s16x4 p = {0, 0, 0, 0};
        if (i4 < 196) {
            float4 v = *(const float4*)(x + (size_t)img * 784 + i4 * 4);
            p[0] = (short)f2bf(v.x); p[1] = (short)f2bf(v.y);
            p[2] = (short)f2bf(v.z); p[3] = (short)f2bf(v.w);
        }
        *(s16x4*)(xb + (size_t)img * XBSZ + i4 * 4) = p;
    }
}

// --------------------------- the fused kernel ------------------------------
__global__ __launch_bounds__(128, 4) void fused_k(const unsigned short* __restrict__ xbf,
                                                  const float* __restrict__ b1,
                                                  const unsigned short* __restrict__ wbuf2,
                                                  const unsigned short* __restrict__ wbuf3,
                                                  const unsigned short* __restrict__ wband,
                                                  const unsigned short* __restrict__ wfb,
                                                  const float* __restrict__ b2,
                                                  const float* __restrict__ b3,
                                                  const float* __restrict__ bf,
                                                  float* __restrict__ out) {
    __shared__ __align__(16) unsigned short sm16[SM_ELEMS];

    const int tid = threadIdx.x;
    const int wave = tid >> 6, lane = tid & 63;
    const int quad = lane >> 4, lm = lane & 15;
    const int img = blockIdx.x * 2 + wave;             // this wave's image

    unsigned short* h1w = sm16 + wave * H1SZ;          // own 4712-elem region

    // ---- zero h1 row pads + c-pads (before conv1 epilogue writes) ---------
    for (int e = lane; e < 95; e += 64) {              // row pads [228,248) x 19
        int row = e / 5, seg = e - row * 5;
        *(s16x4*)(h1w + row * ROW1 + 228 + seg * 4) = (s16x4){0, 0, 0, 0};
    }
    for (int e = lane; e < 361; e += 64) {             // c-pads (oy,ox,[10,12))
        int oy = e / 19, ox = e - oy * 19;
        *(unsigned int*)(h1w + oy * ROW1 + ox * 12 + 10) = 0u;
    }

    // ---- conv1 MFMA  M=32(19), N=192(190), K=288(280) ---------------------
    // A-frags: s16x8 pairs from global xbf16 (L1-hot, tail zeros in-array).
    // kc-loop rolled, dist-0 JIT loads: conv1's register-feasible optimum
    // (r16/r17/r26/r28: any deeper in-flight depth OR larger acc spills).
    {
        const unsigned short* xg = xbf + (size_t)img * XBSZ;
        const int ab0 = lm * 28 + quad * 8;            // <= 444
        int r1 = lm + 16; if (r1 > 18) r1 = 18;        // clamp pad rows
        const int ab1 = r1 * 28 + quad * 8;            // <= 528; +256+7 <= 791 < 800
        const unsigned short* wb = wband + lane * 8;
#pragma unroll 1
        for (int g = 0; g < 2; ++g) {
            f32x4 acc1[6][2] = {};
#pragma unroll 1
            for (int kc = 0; kc < 9; ++kc) {
                s16x8 a0 = cat8(*(const s16x4*)(xg + ab0 + kc * 32),
                                *(const s16x4*)(xg + ab0 + kc * 32 + 4));
                s16x8 a1 = cat8(*(const s16x4*)(xg + ab1 + kc * 32),
                                *(const s16x4*)(xg + ab1 + kc * 32 + 4));
#pragma unroll
                for (int q = 0; q < 6; ++q) {
                    s16x8 bw = *(const s16x8*)(wb + (((g * 6 + q) * 9) + kc) * 512);
                    acc1[q][0] = __builtin_amdgcn_mfma_f32_16x16x32_bf16(a0, bw, acc1[q][0], 0, 0, 0);
                    acc1[q][1] = __builtin_amdgcn_mfma_f32_16x16x32_bf16(a1, bw, acc1[q][1], 0, 0, 0);
                }
            }
#pragma unroll
            for (int q = 0; q < 6; ++q) {
                int n = (g * 6 + q) * 16 + lm;
                if (n < 190) {
                    int ox = n / 10, o = n - ox * 10;
                    float bias = b1[o];
#pragma unroll
                    for (int mt = 0; mt < 2; ++mt) {
#pragma unroll
                        for (int r = 0; r < 4; ++r) {
                            int oy = mt * 16 + quad * 4 + r;
                            if (oy < 19)
                                h1w[oy * ROW1 + ox * 12 + o] =
                                    f2bf(fmaxf(acc1[q][mt][r] + bias, 0.f));
                        }
                    }
                }
            }
        }
    }
    // no runtime barrier: own region, per-wave in-order LDS.

    // ---- conv2 MFMA  M=112(100), N=32(20), K=1280(1000) -------------------
    // 7 m-tiles, single-buffered af[7] (clean shape), dist-1 weights.
    int abase[7];
#pragma unroll
    for (int mt = 0; mt < 7; ++mt) {
        int m = mt * 16 + lm; if (m > 99) m = 99;
        int y = m / 10, xx = m - 10 * y;
        abase[mt] = y * ROW1 + xx * 12 + quad * 8;
    }
    f32x4 acc[7][2] = {};
    {
        const unsigned short* wptr = wbuf2 + lane * 8;
        s16x8 wc0 = *(const s16x8*)(wptr);
        s16x8 wc1 = *(const s16x8*)(wptr + 512);
#pragma unroll
        for (int it = 0; it < 40; ++it) {
            s16x8 wn0 = *(const s16x8*)(wptr + (it + 1) * 1024);   // tail->conv3 region
            s16x8 wn1 = *(const s16x8*)(wptr + (it + 1) * 1024 + 512);
            const unsigned short* sb = h1w + (it >> 2) * ROW1 + (it & 3) * 32;
            s16x8 af[7];
#pragma unroll
            for (int mt = 0; mt < 7; ++mt)
                af[mt] = cat8(*(const s16x4*)(sb + abase[mt]),
                              *(const s16x4*)(sb + abase[mt] + 4));
            __builtin_amdgcn_s_setprio(1);
#pragma unroll
            for (int mt = 0; mt < 7; ++mt) {
                acc[mt][0] = __builtin_amdgcn_mfma_f32_16x16x32_bf16(af[mt], wc0, acc[mt][0], 0, 0, 0);
                acc[mt][1] = __builtin_amdgcn_mfma_f32_16x16x32_bf16(af[mt], wc1, acc[mt][1], 0, 0, 0);
            }
            __builtin_amdgcn_s_setprio(0);
            wc0 = wn0; wc1 = wn1;
        }
    }

    // ---- scatter conv2 -> h2 ([x*20+c], overlays own h1) ------------------
    // h2 cols [200,248) keep stale finite h1 data; weights there are zero.
    unsigned short* h2w = h1w;
#pragma unroll
    for (int mt = 0; mt < 7; ++mt) {
#pragma unroll
        for (int nt = 0; nt < 2; ++nt) {
            int o = nt * 16 + lm;
            if (o < 20) {
                float bias = b2[o];
#pragma unroll
                for (int r = 0; r < 4; ++r) {
                    int pos = mt * 16 + quad * 4 + r;
                    if (pos < 100) {
                        int y2 = pos / 10, x2 = pos - 10 * y2;
                        h2w[y2 * ROW2 + x2 * 20 + o] =
                            f2bf(fmaxf(acc[mt][nt][r] + bias, 0.f));
                    }
                }
            }
        }
    }

    // ---- conv3 MFMA  M=48(36), N=32(20), K=640(500) -----------------------
    // dist-2 weight ring (3 pairs live): ~300cy cover >= L2 latency.
    int abase3[3];
#pragma unroll
    for (int mt = 0; mt < 3; ++mt) {
        int m = mt * 16 + lm; if (m > 35) m = 35;
        int oy = m / 6, ox = m - 6 * oy;
        abase3[mt] = oy * ROW2 + ox * 20 + quad * 8;
    }
    f32x4 acc3[3][2] = {};
    {
        const unsigned short* wptr = wbuf3 + lane * 8;
        s16x8 wA0 = *(const s16x8*)(wptr);
        s16x8 wA1 = *(const s16x8*)(wptr + 512);
        s16x8 wB0 = *(const s16x8*)(wptr + 1024);
        s16x8 wB1 = *(const s16x8*)(wptr + 1024 + 512);
#pragma unroll
        for (int it = 0; it < 20; ++it) {
            // prefetch it+2 (tail reads land in wband region: valid memory)
            s16x8 wC0 = *(const s16x8*)(wptr + (it + 2) * 1024);
            s16x8 wC1 = *(const s16x8*)(wptr + (it + 2) * 1024 + 512);
            const unsigned short* sb = h2w + (it >> 2) * ROW2 + (it & 3) * 32;
            s16x8 af[3];
#pragma unroll
            for (int mt = 0; mt < 3; ++mt)
                af[mt] = cat8(*(const s16x4*)(sb + abase3[mt]),
                              *(const s16x4*)(sb + abase3[mt] + 4));
            __builtin_amdgcn_s_setprio(1);
#pragma unroll
            for (int mt = 0; mt < 3; ++mt) {
                acc3[mt][0] = __builtin_amdgcn_mfma_f32_16x16x32_bf16(af[mt], wA0, acc3[mt][0], 0, 0, 0);
                acc3[mt][1] = __builtin_amdgcn_mfma_f32_16x16x32_bf16(af[mt], wA1, acc3[mt][1], 0, 0, 0);
            }
            __builtin_amdgcn_s_setprio(0);
            wA0 = wB0; wA1 = wB1;                      // rotate ring
            wB0 = wC0; wB1 = wC1;
        }
    }

    // ---- conv3 epilogue -> h3b[o*36+pos] (BF16, relu, overlays own h1) ----
    unsigned short* h3b = h1w;                         // bf16, k-ordered
#pragma unroll
    for (int mt = 0; mt < 3; ++mt) {
#pragma unroll
        for (int nt = 0; nt < 2; ++nt) {
            int o = nt * 16 + lm;
            if (o < 20) {
                float b3v = b3[o];
#pragma unroll
                for (int r = 0; r < 4; ++r) {
                    int pos = mt * 16 + quad * 4 + r;
                    if (pos < 36)
                        h3b[o * 36 + pos] = f2bf(fmaxf(acc3[mt][nt][r] + b3v, 0.f));
                }
            }
        }
    }
    if (lane < 16) h3b[720 + lane] = 0;                // K pad [720,736)

    // ---- fc as MFMA GEMV: broadcast-A (all 16 m-rows = h3) x wf B-frags ---
    // C[row][col] identical across rows; lane holds col = lane&15 in acc[0]
    // (row = quad*4). Lanes 0-9 store out directly. K = 736 = 23 kc.
    {
        const unsigned short* wfp = wfb + lane * 8;
        f32x4 accf = {};
        s16x8 wc = *(const s16x8*)(wfp);
#pragma unroll
        for (int kc = 0; kc < 23; ++kc) {
            s16x8 wn;
            if (kc < 22) wn = *(const s16x8*)(wfp + (kc + 1) * 512);
            s16x8 ah = cat8(*(const s16x4*)(h3b + kc * 32 + quad * 8),
                            *(const s16x4*)(h3b + kc * 32 + quad * 8 + 4));
            accf = __builtin_amdgcn_mfma_f32_16x16x32_bf16(ah, wc, accf, 0, 0, 0);
            if (kc < 22) wc = wn;
        }
        if (lane < 10)
            out[(size_t)img * 10 + lane] = accf[0] + bf[lane];
    }
}

extern "C" void kernel_launch(void* const* d_in, const int* in_sizes, int n_in,
                              void* d_out, int out_size, void* d_ws, size_t ws_size,
                              hipStream_t stream) {
    (void)n_in; (void)out_size; (void)ws_size;
    const float* x  = (const float*)d_in[0];
    const float* w1 = (const float*)d_in[1];
    const float* b1 = (const float*)d_in[2];
    const float* w2 = (const float*)d_in[3];
    const float* b2 = (const float*)d_in[4];
    const float* w3 = (const float*)d_in[5];
    const float* b3 = (const float*)d_in[6];
    const float* wf = (const float*)d_in[7];
    const float* bf = (const float*)d_in[8];
    float* out = (float*)d_out;

    const int B = in_sizes[0] / 784;                   // 4096

    unsigned short* wbuf  = (unsigned short*)d_ws;     // 128512 ushorts = 257 KB
    unsigned short* xbf16 = wbuf + 128512;             // B*800 ushorts = 6.4 MB

    const int total4 = B * 200;                        // s16x4 units
    const int xblocks = (total4 + 255) / 256;
    prep_k<<<WPREP_BLOCKS + xblocks, 256, 0, stream>>>(w1, w2, w3, wf, x,
                                                       wbuf, xbf16, total4);
    fused_k<<<B / 2, 128, 0, stream>>>(xbf16, b1, wbuf, wbuf + 40960,
                                       wbuf + 61440, wbuf + 116736,
                                       b2, b3, bf, out);
}